// Round 3
// baseline (22.330 us; speedup 1.0000x reference)
//
#include <hip/hip_runtime.h>

#define BB 8
#define SS 4096
#define DD 1024
#define TEMP 0.1f
#define PADV -100.0f
#define EPSV 1e-8f

// One block (1024 threads) per batch. Each thread scans 4 labels (int4),
// wave-level shfl scan + one LDS cross-wave combine gives compacted offsets.
// Writes idx[b][j], cnt[b], valid labels as float, plus -100 pads for
// slots >= cnt (disjoint from valid slots, no race).
__global__ __launch_bounds__(1024) void compact_kernel(const int* __restrict__ labels,
                                                       int* __restrict__ idx,
                                                       int* __restrict__ cnt,
                                                       float* __restrict__ out_lab) {
    int b = blockIdx.x;
    int t = threadIdx.x;
    int lane = t & 63, wave = t >> 6;

    int4 v = ((const int4*)(labels + b * SS))[t];
    int vals[4] = {v.x, v.y, v.z, v.w};
    int mycnt = (vals[0] != -100) + (vals[1] != -100) + (vals[2] != -100) + (vals[3] != -100);

    int scan = mycnt;
#pragma unroll
    for (int off = 1; off < 64; off <<= 1) {
        int n = __shfl_up(scan, off, 64);
        if (lane >= off) scan += n;
    }

    __shared__ int wsum[16];
    if (lane == 63) wsum[wave] = scan;
    __syncthreads();

    int wbase = 0, total = 0;
#pragma unroll
    for (int w = 0; w < 16; ++w) {
        int s = wsum[w];
        wbase += (w < wave) ? s : 0;
        total += s;
    }

    if (t == 0) cnt[b] = total;

    int o = wbase + scan - mycnt;
#pragma unroll
    for (int i = 0; i < 4; ++i) {
        if (vals[i] != -100) {
            idx[b * SS + o]     = 4 * t + i;
            out_lab[b * SS + o] = (float)vals[i];
            ++o;
        }
    }
#pragma unroll
    for (int i = 0; i < 4; ++i) {
        int s = 4 * t + i;
        if (s >= total) out_lab[b * SS + s] = PADV;
    }
}

// One WAVE per 8 consecutive ranks. Chain reuse: pair j's B-vector becomes
// pair j+1's A-vector -> 9 vector loads per 8 pairs, each norm computed once.
// After shfl_xor butterfly all lanes hold the sums, so lane k keeps pair k's
// result and lanes 0..7 do one contiguous 8-float store.
__global__ __launch_bounds__(256) void cos_kernel(const float* __restrict__ x,
                                                  const int* __restrict__ idx,
                                                  const int* __restrict__ cnt,
                                                  float* __restrict__ out_cos) {
    int b    = blockIdx.y;
    int lane = threadIdx.x & 63;
    int wid  = threadIdx.x >> 6;
    int j0   = (blockIdx.x * 4 + wid) * 8;
    int c    = cnt[b];

    float* outp = out_cos + b * SS + j0;
    if (j0 >= c) {
        if (lane < 8) outp[lane] = PADV;
        return;
    }

    const int*   ib = idx + b * SS;
    const float* xb = x + (size_t)b * SS * DD;

    // Load A = vec(idx[j0]) and reduce its norm.
    const float* pa = xb + (size_t)ib[j0] * DD;
    float4 A0 = *(const float4*)(pa + 0 * 256 + lane * 4);
    float4 A1 = *(const float4*)(pa + 1 * 256 + lane * 4);
    float4 A2 = *(const float4*)(pa + 2 * 256 + lane * 4);
    float4 A3 = *(const float4*)(pa + 3 * 256 + lane * 4);
    float na = A0.x*A0.x + A0.y*A0.y + A0.z*A0.z + A0.w*A0.w
             + A1.x*A1.x + A1.y*A1.y + A1.z*A1.z + A1.w*A1.w
             + A2.x*A2.x + A2.y*A2.y + A2.z*A2.z + A2.w*A2.w
             + A3.x*A3.x + A3.y*A3.y + A3.z*A3.z + A3.w*A3.w;
#pragma unroll
    for (int off = 32; off; off >>= 1) na += __shfl_xor(na, off, 64);

    float myres = PADV;
#pragma unroll
    for (int k = 0; k < 8; ++k) {
        int j = j0 + k;
        if (j < c) {
            int jn = (j + 1 == c) ? 0 : (j + 1);
            const float* pb = xb + (size_t)ib[jn] * DD;
            float4 B0 = *(const float4*)(pb + 0 * 256 + lane * 4);
            float4 B1 = *(const float4*)(pb + 1 * 256 + lane * 4);
            float4 B2 = *(const float4*)(pb + 2 * 256 + lane * 4);
            float4 B3 = *(const float4*)(pb + 3 * 256 + lane * 4);

            float dot = A0.x*B0.x + A0.y*B0.y + A0.z*B0.z + A0.w*B0.w
                      + A1.x*B1.x + A1.y*B1.y + A1.z*B1.z + A1.w*B1.w
                      + A2.x*B2.x + A2.y*B2.y + A2.z*B2.z + A2.w*B2.w
                      + A3.x*B3.x + A3.y*B3.y + A3.z*B3.z + A3.w*B3.w;
            float nb = B0.x*B0.x + B0.y*B0.y + B0.z*B0.z + B0.w*B0.w
                     + B1.x*B1.x + B1.y*B1.y + B1.z*B1.z + B1.w*B1.w
                     + B2.x*B2.x + B2.y*B2.y + B2.z*B2.z + B2.w*B2.w
                     + B3.x*B3.x + B3.y*B3.y + B3.z*B3.z + B3.w*B3.w;
#pragma unroll
            for (int off = 32; off; off >>= 1) {
                dot += __shfl_xor(dot, off, 64);
                nb  += __shfl_xor(nb,  off, 64);
            }
            float r = dot / fmaxf(sqrtf(na) * sqrtf(nb), EPSV) / TEMP;
            if (lane == k) myres = r;

            A0 = B0; A1 = B1; A2 = B2; A3 = B3;
            na = nb;
        }
    }
    if (lane < 8) outp[lane] = myres;   // myres stays PADV for ranks >= c
}

extern "C" void kernel_launch(void* const* d_in, const int* in_sizes, int n_in,
                              void* d_out, int out_size, void* d_ws, size_t ws_size,
                              hipStream_t stream) {
    const float* seq    = (const float*)d_in[0];   // [B,S,D] f32
    const int*   labels = (const int*)d_in[1];     // [B,S] i32

    float* out_cos = (float*)d_out;                // [B,S]
    float* out_lab = (float*)d_out + BB * SS;      // [B,S] as floats

    int* idx = (int*)d_ws;                         // B*S ints
    int* cnt = idx + BB * SS;                      // B ints

    compact_kernel<<<BB, 1024, 0, stream>>>(labels, idx, cnt, out_lab);

    dim3 grid(SS / 32, BB);                        // 4 waves/block, 8 ranks/wave
    cos_kernel<<<grid, 256, 0, stream>>>(seq, idx, cnt, out_cos);
}

// Round 4
// 16.877 us; speedup vs baseline: 1.3231x; 1.3231x over previous
//
#include <hip/hip_runtime.h>

#define BB 8
#define SS 4096
#define DD 1024
#define TEMP 0.1f
#define PADV -100.0f
#define EPSV 1e-8f

// One block (1024 threads) per batch. Each thread scans 4 labels (int4),
// wave-level shfl scan + LDS cross-wave combine -> compacted offsets.
// Writes idx[b][j], cnt[b], valid labels (as float), AND all -100 pads for
// BOTH output chunks (slots >= cnt) so the cos kernel touches only valid ranks.
__global__ __launch_bounds__(1024) void compact_kernel(const int* __restrict__ labels,
                                                       int* __restrict__ idx,
                                                       int* __restrict__ cnt,
                                                       float* __restrict__ out_cos,
                                                       float* __restrict__ out_lab) {
    int b = blockIdx.x;
    int t = threadIdx.x;
    int lane = t & 63, wave = t >> 6;

    int4 v = ((const int4*)(labels + b * SS))[t];
    int vals[4] = {v.x, v.y, v.z, v.w};
    int mycnt = (vals[0] != -100) + (vals[1] != -100) + (vals[2] != -100) + (vals[3] != -100);

    int scan = mycnt;
#pragma unroll
    for (int off = 1; off < 64; off <<= 1) {
        int n = __shfl_up(scan, off, 64);
        if (lane >= off) scan += n;
    }

    __shared__ int wsum[16];
    if (lane == 63) wsum[wave] = scan;
    __syncthreads();

    int wbase = 0, total = 0;
#pragma unroll
    for (int w = 0; w < 16; ++w) {
        int s = wsum[w];
        wbase += (w < wave) ? s : 0;
        total += s;
    }

    if (t == 0) cnt[b] = total;

    int o = wbase + scan - mycnt;
#pragma unroll
    for (int i = 0; i < 4; ++i) {
        if (vals[i] != -100) {
            idx[b * SS + o]     = 4 * t + i;
            out_lab[b * SS + o] = (float)vals[i];
            ++o;
        }
    }
    // label pads
#pragma unroll
    for (int i = 0; i < 4; ++i) {
        int s = 4 * t + i;
        if (s >= total) out_lab[b * SS + s] = PADV;
    }
    // cosine pads (cos kernel writes only slots < cnt)
    for (int s = total + t; s < SS; s += 1024) out_cos[b * SS + s] = PADV;
}

// One WAVE per 2 consecutive ranks. Three vectors A,B,C loaded IN PARALLEL
// (no chain dependency): 1.5 vector loads per pair, shared middle norm.
// Butterfly over 5 partials; every lane ends with all sums, lanes 0/1 store.
__global__ __launch_bounds__(256) void cos_kernel(const float* __restrict__ x,
                                                  const int* __restrict__ idx,
                                                  const int* __restrict__ cnt,
                                                  float* __restrict__ out_cos) {
    int b    = blockIdx.y;
    int lane = threadIdx.x & 63;
    int wid  = threadIdx.x >> 6;
    int j0   = (blockIdx.x * 4 + wid) * 2;
    int c    = cnt[b];
    if (j0 >= c) return;                     // pads already written by compact

    const int* ib = idx + b * SS;
    int i0  = ib[j0];
    int jn0 = (j0 + 1 == c) ? 0 : (j0 + 1);
    int i1  = ib[jn0];
    bool p1 = (j0 + 1 < c);
    int jn1 = (j0 + 2 == c) ? 0 : (j0 + 2);
    int i2  = p1 ? ib[jn1] : i1;

    const float* xb = x + (size_t)b * SS * DD + (size_t)lane * 4;
    const float* pa = xb + (size_t)i0 * DD;
    const float* pb = xb + (size_t)i1 * DD;
    const float* pc = xb + (size_t)i2 * DD;

    float4 A[4], B[4], C[4];
#pragma unroll
    for (int q = 0; q < 4; ++q) {
        A[q] = *(const float4*)(pa + q * 256);
        B[q] = *(const float4*)(pb + q * 256);
        C[q] = *(const float4*)(pc + q * 256);
    }

    float na = 0.f, nb = 0.f, nc = 0.f, dab = 0.f, dbc = 0.f;
#pragma unroll
    for (int q = 0; q < 4; ++q) {
        na  += A[q].x*A[q].x + A[q].y*A[q].y + A[q].z*A[q].z + A[q].w*A[q].w;
        nb  += B[q].x*B[q].x + B[q].y*B[q].y + B[q].z*B[q].z + B[q].w*B[q].w;
        nc  += C[q].x*C[q].x + C[q].y*C[q].y + C[q].z*C[q].z + C[q].w*C[q].w;
        dab += A[q].x*B[q].x + A[q].y*B[q].y + A[q].z*B[q].z + A[q].w*B[q].w;
        dbc += B[q].x*C[q].x + B[q].y*C[q].y + B[q].z*C[q].z + B[q].w*C[q].w;
    }
#pragma unroll
    for (int off = 32; off; off >>= 1) {
        na  += __shfl_xor(na,  off, 64);
        nb  += __shfl_xor(nb,  off, 64);
        nc  += __shfl_xor(nc,  off, 64);
        dab += __shfl_xor(dab, off, 64);
        dbc += __shfl_xor(dbc, off, 64);
    }

    if (lane == 0)
        out_cos[b * SS + j0] = dab / fmaxf(sqrtf(na) * sqrtf(nb), EPSV) / TEMP;
    if (lane == 1 && p1)
        out_cos[b * SS + j0 + 1] = dbc / fmaxf(sqrtf(nb) * sqrtf(nc), EPSV) / TEMP;
}

extern "C" void kernel_launch(void* const* d_in, const int* in_sizes, int n_in,
                              void* d_out, int out_size, void* d_ws, size_t ws_size,
                              hipStream_t stream) {
    const float* seq    = (const float*)d_in[0];   // [B,S,D] f32
    const int*   labels = (const int*)d_in[1];     // [B,S] i32

    float* out_cos = (float*)d_out;                // [B,S]
    float* out_lab = (float*)d_out + BB * SS;      // [B,S] as floats

    int* idx = (int*)d_ws;                         // B*S ints
    int* cnt = idx + BB * SS;                      // B ints

    compact_kernel<<<BB, 1024, 0, stream>>>(labels, idx, cnt, out_cos, out_lab);

    dim3 grid(SS / 8, BB);                         // 4 waves/block, 2 ranks/wave
    cos_kernel<<<grid, 256, 0, stream>>>(seq, idx, cnt, out_cos);
}